// Round 4
// baseline (258.991 us; speedup 1.0000x reference)
//
#include <hip/hip_runtime.h>
#include <math.h>

#define B 8
#define D 256
#define N_LIVE 10000
#define K_NEW 32
#define KC 10032
#define NS 100
#define NROW 101            // 100 bootstrap rows + 1 plain-softmax row (the score)
#define EPS 0.1f
#define CAP 1024            // active-set capacity (expected ~75 per b)
#define ACT_CUT 87.0f       // exp(-87)=1.65e-38: below fp32-normal -> weight 0 anyway

// ---- workspace layout in floats ----
// header: Mglob[b] at stride 16 (cache-line padded) + act_cnt[8] at [128..135]
#define WS_HDR    0                            // 160 ints
#define WS_LOGITS 160                          // B*KC floats
#define WS_ACTE   (WS_LOGITS + B * KC)         // B*CAP floats: e_j = exp(l-M)
#define WS_ACTI   (WS_ACTE + B * CAP)          // B*CAP ints: particle index j
#define WS_LUT    (WS_ACTI + B * CAP)          // B*KC ushorts = B*KC/2 floats
#define WS_BOOT   (WS_LUT + B * KC / 2)        // B*NROW*D floats   (~1.38 MB total)

__device__ __forceinline__ unsigned enc_f32(float f) {
  unsigned x = __float_as_uint(f);
  return (x & 0x80000000u) ? ~x : (x | 0x80000000u);   // order-preserving
}
__device__ __forceinline__ float dec_f32(unsigned k) {
  return __uint_as_float((k & 0x80000000u) ? (k & 0x7FFFFFFFu) : ~k);
}

// ---------------- kernel 1: logits[b,k] + per-b running max ----------------
// one 64-lane wave per particle; 4 particles per 256-thread block
__global__ __launch_bounds__(256) void k_logits(
    const float* __restrict__ xt, const float* __restrict__ live_x0,
    const float* __restrict__ live_ll, const float* __restrict__ x0n,
    const float* __restrict__ lln, const float* __restrict__ ts_p,
    float* __restrict__ logits, unsigned* __restrict__ hdr) {
  int b = blockIdx.y;
  int k = blockIdx.x * 4 + (threadIdx.x >> 6);
  int lane = threadIdx.x & 63;
  const float* src = (k < N_LIVE)
      ? (live_x0 + ((size_t)b * N_LIVE + k) * D)
      : (x0n + ((size_t)b * K_NEW + (k - N_LIVE)) * D);
  float4 v = ((const float4*)src)[lane];
  float4 c = ((const float4*)(xt + b * D))[lane];
  float dx = v.x - c.x, dy = v.y - c.y, dz = v.z - c.z, dw = v.w - c.w;
  float s = dx * dx + dy * dy + dz * dz + dw * dw;
#pragma unroll
  for (int off = 32; off; off >>= 1) s += __shfl_xor(s, off);
  __shared__ float wlog[4];
  if (lane == 0) {
    float ts = *ts_p;
    float out;
    if (k < N_LIVE)
      out = live_ll[(size_t)b * N_LIVE + k] - 0.5f * s / (ts * ts) - logf(ts);
    else
      out = lln[(size_t)b * K_NEW + (k - N_LIVE)];  // gaussian corr cancels exactly
    logits[(size_t)b * KC + k] = out;
    wlog[threadIdx.x >> 6] = out;
  }
  __syncthreads();
  if (threadIdx.x == 0) {
    float m = fmaxf(fmaxf(wlog[0], wlog[1]), fmaxf(wlog[2], wlog[3]));
    atomicMax(&hdr[b * 16], enc_f32(m));   // one atomic per block, padded line
  }
}

// ---------------- kernel 2: active-set selection ----------------
// Active = logit within ACT_CUT of the per-b max; everything else has
// exp(l-M) below fp32-normal range -> weight 0 in fp32. ~75 actives per b.
__global__ __launch_bounds__(256) void k_select(
    const float* __restrict__ logits, unsigned* __restrict__ hdr,
    float* __restrict__ act_e, int* __restrict__ act_idx,
    unsigned short* __restrict__ lut) {
  int b = blockIdx.y;
  int tid = blockIdx.x * 256 + threadIdx.x;   // 8 blocks per b
  float M = dec_f32(hdr[b * 16]);
  const float* lg = logits + (size_t)b * KC;
  int* cnt = (int*)&hdr[128 + b];
  for (int k = tid; k < KC; k += 8 * 256) {
    float l = lg[k];
    unsigned short v = 0;
    if (l > M - ACT_CUT) {
      int pos = atomicAdd(cnt, 1);
      if (pos < CAP) {
        act_e[b * CAP + pos] = expf(l - M);
        act_idx[b * CAP + pos] = k;
        v = (unsigned short)(pos + 1);
      }
    }
    lut[(size_t)b * KC + k] = v;
  }
}

// ---------------- kernel 3: fused count + sparse weighted sum ----------------
// One block per (n,b). Counts occurrences of active particles in the bootstrap
// row (uint16 lut: 20KB/b -> L1-resident; LDS atomics only on ~75 hits), then
// boot[n,b,d] = sum_j c_j e_j x[j,d] / sum_j c_j e_j over the nonzero actives.
// n==100 is the identity row (plain softmax -> final score).
__global__ __launch_bounds__(256) void k_boot(
    const float* __restrict__ live_x0, const float* __restrict__ x0n,
    const float* __restrict__ act_e, const int* __restrict__ act_idx,
    const unsigned* __restrict__ hdr, const unsigned short* __restrict__ lut,
    const int* __restrict__ boot_idx, float* __restrict__ boot) {
  int n = blockIdx.x;   // 0..100
  int b = blockIdx.y;
  int tid = threadIdx.x;
  __shared__ int cnt[CAP];
  __shared__ float wval[CAP];
  __shared__ int widx[CAP];
  __shared__ int snnz;
  __shared__ float sden[4];
  int A = min((int)hdr[128 + b], CAP);
  for (int i = tid; i < A; i += 256) cnt[i] = 0;
  if (tid == 0) snnz = 0;
  __syncthreads();

  if (n < NS) {
    const int4* row = (const int4*)(boot_idx + ((size_t)n * B + b) * KC);
    const unsigned short* lutb = lut + (size_t)b * KC;
    for (int k = tid; k < KC / 4; k += 256) {   // KC%4==0
      int4 v = row[k];
      int t;
      t = lutb[v.x]; if (t) atomicAdd(&cnt[t - 1], 1);
      t = lutb[v.y]; if (t) atomicAdd(&cnt[t - 1], 1);
      t = lutb[v.z]; if (t) atomicAdd(&cnt[t - 1], 1);
      t = lutb[v.w]; if (t) atomicAdd(&cnt[t - 1], 1);
    }
  } else {
    for (int i = tid; i < A; i += 256) cnt[i] = 1;
  }
  __syncthreads();

  // compact nonzero actives + denominator
  float dpart = 0.f;
  for (int i = tid; i < A; i += 256) {
    int c = cnt[i];
    if (c) {
      float w = (float)c * act_e[b * CAP + i];
      int pos = atomicAdd(&snnz, 1);
      wval[pos] = w;
      widx[pos] = act_idx[b * CAP + i];
      dpart += w;
    }
  }
#pragma unroll
  for (int off = 32; off; off >>= 1) dpart += __shfl_xor(dpart, off);
  if ((tid & 63) == 0) sden[tid >> 6] = dpart;
  __syncthreads();
  float inv = 1.f / (sden[0] + sden[1] + sden[2] + sden[3]);
  int nnz = snnz;

  const float* lx = live_x0 + (size_t)b * N_LIVE * D;
  const float* nx = x0n + (size_t)b * K_NEW * D;
  float acc0 = 0.f, acc1 = 0.f;
  int p = 0;
  for (; p + 1 < nnz; p += 2) {        // 2-way unroll: more loads in flight
    int j0 = widx[p], j1 = widx[p + 1];
    const float* r0 = (j0 < N_LIVE) ? (lx + (size_t)j0 * D) : (nx + (size_t)(j0 - N_LIVE) * D);
    const float* r1 = (j1 < N_LIVE) ? (lx + (size_t)j1 * D) : (nx + (size_t)(j1 - N_LIVE) * D);
    float x0v = r0[tid], x1v = r1[tid];
    acc0 = fmaf(wval[p], x0v, acc0);
    acc1 = fmaf(wval[p + 1], x1v, acc1);
  }
  if (p < nnz) {
    int j = widx[p];
    const float* xr = (j < N_LIVE) ? (lx + (size_t)j * D) : (nx + (size_t)(j - N_LIVE) * D);
    acc0 = fmaf(wval[p], xr[tid], acc0);
  }
  boot[((size_t)b * NROW + n) * D + tid] = (acc0 + acc1) * inv;
}

// ---------------- kernel 4: std over bootstrap rows + epilogue ----------------
__global__ __launch_bounds__(256) void k_final(
    const float* __restrict__ boot, const float* __restrict__ xt,
    const float* __restrict__ ts_p, float* __restrict__ out) {
  int b = blockIdx.x;
  int d = threadIdx.x;
  float ts = *ts_p;
  const float* bb = boot + (size_t)b * NROW * D + d;
  float sum = 0.f;
  for (int n = 0; n < NS; n++) sum += bb[(size_t)n * D];
  float mean = sum / (float)NS;
  float vs = 0.f;
  for (int n = 0; n < NS; n++) { float t = bb[(size_t)n * D] - mean; vs += t * t; }
  float sigma_raw = sqrtf(vs / (float)(NS - 1));
  // std((x - xt)/ts) = std(x)/ts   (ts > 0); condition: sigma_v < EPS*ts
  bool ok = (sigma_raw / ts) < (EPS * ts);
  // score = (sum_k w*x - xt)/ts  since sum_k w == 1
  out[(size_t)b * D + d] = (bb[(size_t)NS * D] - xt[(size_t)b * D + d]) / ts;
  unsigned long long m = __ballot(ok);
  __shared__ int wok[4];
  if ((d & 63) == 0) wok[d >> 6] = (m == 0xFFFFFFFFFFFFFFFFull) ? 1 : 0;
  __syncthreads();
  if (d == 0) out[(size_t)B * D + b] = (wok[0] & wok[1] & wok[2] & wok[3]) ? 1.0f : 0.0f;
}

extern "C" void kernel_launch(void* const* d_in, const int* in_sizes, int n_in,
                              void* d_out, int out_size, void* d_ws, size_t ws_size,
                              hipStream_t stream) {
  const float* xt       = (const float*)d_in[0];
  const float* live_x0  = (const float*)d_in[1];
  const float* live_ll  = (const float*)d_in[2];
  const float* x0n      = (const float*)d_in[3];
  const float* lln      = (const float*)d_in[4];
  const float* ts_p     = (const float*)d_in[5];
  const int*   boot_idx = (const int*)d_in[6];
  float* out = (float*)d_out;
  float* ws  = (float*)d_ws;

  unsigned* hdr            = (unsigned*)(ws + WS_HDR);
  float* logits            = ws + WS_LOGITS;
  float* act_e             = ws + WS_ACTE;
  int*   act_idx           = (int*)(ws + WS_ACTI);
  unsigned short* lut      = (unsigned short*)(ws + WS_LUT);
  float* boot              = ws + WS_BOOT;

  // zero header (Mglob encodings + act_cnt); ws is poisoned 0xAA each call
  hipMemsetAsync(hdr, 0, 160 * sizeof(unsigned), stream);

  k_logits<<<dim3(KC / 4, B), 256, 0, stream>>>(xt, live_x0, live_ll, x0n, lln, ts_p, logits, hdr);
  k_select<<<dim3(8, B), 256, 0, stream>>>(logits, hdr, act_e, act_idx, lut);
  k_boot<<<dim3(NROW, B), 256, 0, stream>>>(live_x0, x0n, act_e, act_idx, hdr, lut, boot_idx, boot);
  k_final<<<dim3(B), 256, 0, stream>>>(boot, xt, ts_p, out);
}

// Round 5
// 189.274 us; speedup vs baseline: 1.3683x; 1.3683x over previous
//
#include <hip/hip_runtime.h>
#include <math.h>

#define B 8
#define D 256
#define N_LIVE 10000
#define K_NEW 32
#define KC 10032
#define NS 100
#define NROW 101            // 100 bootstrap rows + 1 plain-softmax row (the score)
#define EPS 0.1f
#define CAP 1024            // active-set capacity (expected ~75 per b)
#define ACT_CUT 87.0f       // exp(-87)=1.65e-38: below fp32-normal -> weight 0 anyway
#define LBLK 627            // k_logits blocks per b (16 particles each)
#define BMAX_STRIDE 640

// ---- workspace layout in floats ----
// hdr: M[b] at stride 16 (line-padded) + act_cnt[8] at [128..135]
#define WS_HDR    0                            // 160 ints
#define WS_BMAX   160                          // B*640 floats: per-block maxima
#define WS_LOGITS (WS_BMAX + B * BMAX_STRIDE)  // B*KC floats
#define WS_ACTE   (WS_LOGITS + B * KC)         // B*CAP floats: e_j = exp(l-M)
#define WS_ACTI   (WS_ACTE + B * CAP)          // B*CAP ints: particle index j
#define WS_LUT    (WS_ACTI + B * CAP)          // B*KC ushorts = B*KC/2 floats
#define WS_BOOT   (WS_LUT + B * KC / 2)        // B*NROW*D floats   (~1.4 MB total)

// ---------------- kernel 1: logits[b,k] + per-block max ----------------
// 4 particles per wave (16/block): 4 independent float4 loads in flight,
// 4 interleaved shuffle-reduce chains. NO global atomics (r4 lesson: 20k
// atomicMax onto 8 lines serialized ~50us).
__global__ __launch_bounds__(256) void k_logits(
    const float* __restrict__ xt, const float* __restrict__ live_x0,
    const float* __restrict__ live_ll, const float* __restrict__ x0n,
    const float* __restrict__ lln, const float* __restrict__ ts_p,
    float* __restrict__ logits, float* __restrict__ bmax) {
  int b = blockIdx.y;
  int w = threadIdx.x >> 6;
  int lane = threadIdx.x & 63;
  int k0 = blockIdx.x * 16 + w * 4;          // quad-aligned; N_LIVE%4==0 -> no straddle
  float4 c = ((const float4*)(xt + b * D))[lane];

  float s[4];
#pragma unroll
  for (int p = 0; p < 4; p++) {
    int k = k0 + p;
    const float* src = (k < N_LIVE)
        ? (live_x0 + ((size_t)b * N_LIVE + k) * D)
        : (x0n + ((size_t)b * K_NEW + (k - N_LIVE)) * D);
    float4 v = ((const float4*)src)[lane];
    float dx = v.x - c.x, dy = v.y - c.y, dz = v.z - c.z, dw = v.w - c.w;
    s[p] = dx * dx + dy * dy + dz * dz + dw * dw;
  }
#pragma unroll
  for (int off = 32; off; off >>= 1) {       // 4 independent chains -> ILP hides DS latency
    s[0] += __shfl_xor(s[0], off);
    s[1] += __shfl_xor(s[1], off);
    s[2] += __shfl_xor(s[2], off);
    s[3] += __shfl_xor(s[3], off);
  }
  __shared__ float wlog[4];
  if (lane == 0) {
    float ts = *ts_p;
    float inv2 = 0.5f / (ts * ts), lts = logf(ts);
    float4 o;
    float* ov = &o.x;
#pragma unroll
    for (int p = 0; p < 4; p++) {
      int k = k0 + p;
      ov[p] = (k < N_LIVE)
          ? live_ll[(size_t)b * N_LIVE + k] - s[p] * inv2 - lts
          : lln[(size_t)b * K_NEW + (k - N_LIVE)];   // gaussian corr cancels exactly
    }
    *(float4*)(logits + (size_t)b * KC + k0) = o;
    wlog[w] = fmaxf(fmaxf(o.x, o.y), fmaxf(o.z, o.w));
  }
  __syncthreads();
  if (threadIdx.x == 0)
    bmax[b * BMAX_STRIDE + blockIdx.x] =
        fmaxf(fmaxf(wlog[0], wlog[1]), fmaxf(wlog[2], wlog[3]));
}

// ---------------- kernel 1b: reduce per-block maxima -> M[b] ----------------
__global__ __launch_bounds__(256) void k_bmax(
    const float* __restrict__ bmax, float* __restrict__ hdr) {
  int b = blockIdx.x;
  int tid = threadIdx.x;
  float m = -INFINITY;
  for (int i = tid; i < LBLK; i += 256) m = fmaxf(m, bmax[b * BMAX_STRIDE + i]);
#pragma unroll
  for (int off = 32; off; off >>= 1) m = fmaxf(m, __shfl_xor(m, off));
  __shared__ float sm[4];
  if ((tid & 63) == 0) sm[tid >> 6] = m;
  __syncthreads();
  if (tid == 0)
    hdr[b * 16] = fmaxf(fmaxf(sm[0], sm[1]), fmaxf(sm[2], sm[3]));  // plain store
}

// ---------------- kernel 2: active-set selection ----------------
// Active = logit within ACT_CUT of the per-b max; everything else has
// exp(l-M) below fp32-normal range -> weight 0 in fp32. ~75 actives per b.
__global__ __launch_bounds__(256) void k_select(
    const float* __restrict__ logits, const float* __restrict__ hdrM,
    unsigned* __restrict__ hdr, float* __restrict__ act_e,
    int* __restrict__ act_idx, unsigned short* __restrict__ lut) {
  int b = blockIdx.y;
  int tid = blockIdx.x * 256 + threadIdx.x;   // 8 blocks per b
  float M = hdrM[b * 16];
  const float* lg = logits + (size_t)b * KC;
  int* cnt = (int*)&hdr[128 + b];
  for (int k = tid; k < KC; k += 8 * 256) {
    float l = lg[k];
    unsigned short v = 0;
    if (l > M - ACT_CUT) {
      int pos = atomicAdd(cnt, 1);            // rare: ~75 per b total
      if (pos < CAP) {
        act_e[b * CAP + pos] = expf(l - M);
        act_idx[b * CAP + pos] = k;
        v = (unsigned short)(pos + 1);
      }
    }
    lut[(size_t)b * KC + k] = v;
  }
}

// ---------------- kernel 3: fused count + sparse weighted sum ----------------
// One block per (n,b). Counts occurrences of active particles in the bootstrap
// row (uint16 lut: 20KB/b -> L1-resident; LDS atomics only on ~75 hits), then
// boot[n,b,d] = sum_j c_j e_j x[j,d] / sum_j c_j e_j over the nonzero actives.
// n==100 is the identity row (plain softmax -> final score).
__global__ __launch_bounds__(256) void k_boot(
    const float* __restrict__ live_x0, const float* __restrict__ x0n,
    const float* __restrict__ act_e, const int* __restrict__ act_idx,
    const unsigned* __restrict__ hdr, const unsigned short* __restrict__ lut,
    const int* __restrict__ boot_idx, float* __restrict__ boot) {
  int n = blockIdx.x;   // 0..100
  int b = blockIdx.y;
  int tid = threadIdx.x;
  __shared__ int cnt[CAP];
  __shared__ float wval[CAP];
  __shared__ int widx[CAP];
  __shared__ int snnz;
  __shared__ float sden[4];
  int A = min((int)hdr[128 + b], CAP);
  for (int i = tid; i < A; i += 256) cnt[i] = 0;
  if (tid == 0) snnz = 0;
  __syncthreads();

  if (n < NS) {
    const int4* row = (const int4*)(boot_idx + ((size_t)n * B + b) * KC);
    const unsigned short* lutb = lut + (size_t)b * KC;
    for (int k = tid; k < KC / 4; k += 256) {   // KC%4==0
      int4 v = row[k];
      int t;
      t = lutb[v.x]; if (t) atomicAdd(&cnt[t - 1], 1);
      t = lutb[v.y]; if (t) atomicAdd(&cnt[t - 1], 1);
      t = lutb[v.z]; if (t) atomicAdd(&cnt[t - 1], 1);
      t = lutb[v.w]; if (t) atomicAdd(&cnt[t - 1], 1);
    }
  } else {
    for (int i = tid; i < A; i += 256) cnt[i] = 1;
  }
  __syncthreads();

  // compact nonzero actives + denominator
  float dpart = 0.f;
  for (int i = tid; i < A; i += 256) {
    int c = cnt[i];
    if (c) {
      float w = (float)c * act_e[b * CAP + i];
      int pos = atomicAdd(&snnz, 1);
      wval[pos] = w;
      widx[pos] = act_idx[b * CAP + i];
      dpart += w;
    }
  }
#pragma unroll
  for (int off = 32; off; off >>= 1) dpart += __shfl_xor(dpart, off);
  if ((tid & 63) == 0) sden[tid >> 6] = dpart;
  __syncthreads();
  float inv = 1.f / (sden[0] + sden[1] + sden[2] + sden[3]);
  int nnz = snnz;

  const float* lx = live_x0 + (size_t)b * N_LIVE * D;
  const float* nx = x0n + (size_t)b * K_NEW * D;
  float acc0 = 0.f, acc1 = 0.f;
  int p = 0;
  for (; p + 1 < nnz; p += 2) {        // 2-way unroll: more loads in flight
    int j0 = widx[p], j1 = widx[p + 1];
    const float* r0 = (j0 < N_LIVE) ? (lx + (size_t)j0 * D) : (nx + (size_t)(j0 - N_LIVE) * D);
    const float* r1 = (j1 < N_LIVE) ? (lx + (size_t)j1 * D) : (nx + (size_t)(j1 - N_LIVE) * D);
    float x0v = r0[tid], x1v = r1[tid];
    acc0 = fmaf(wval[p], x0v, acc0);
    acc1 = fmaf(wval[p + 1], x1v, acc1);
  }
  if (p < nnz) {
    int j = widx[p];
    const float* xr = (j < N_LIVE) ? (lx + (size_t)j * D) : (nx + (size_t)(j - N_LIVE) * D);
    acc0 = fmaf(wval[p], xr[tid], acc0);
  }
  boot[((size_t)b * NROW + n) * D + tid] = (acc0 + acc1) * inv;
}

// ---------------- kernel 4: std over bootstrap rows + epilogue ----------------
__global__ __launch_bounds__(256) void k_final(
    const float* __restrict__ boot, const float* __restrict__ xt,
    const float* __restrict__ ts_p, float* __restrict__ out) {
  int b = blockIdx.x;
  int d = threadIdx.x;
  float ts = *ts_p;
  const float* bb = boot + (size_t)b * NROW * D + d;
  float sum = 0.f;
#pragma unroll 4
  for (int n = 0; n < NS; n++) sum += bb[(size_t)n * D];
  float mean = sum / (float)NS;
  float vs = 0.f;
#pragma unroll 4
  for (int n = 0; n < NS; n++) { float t = bb[(size_t)n * D] - mean; vs += t * t; }
  float sigma_raw = sqrtf(vs / (float)(NS - 1));
  // std((x - xt)/ts) = std(x)/ts   (ts > 0); condition: sigma_v < EPS*ts
  bool ok = (sigma_raw / ts) < (EPS * ts);
  // score = (sum_k w*x - xt)/ts  since sum_k w == 1
  out[(size_t)b * D + d] = (bb[(size_t)NS * D] - xt[(size_t)b * D + d]) / ts;
  unsigned long long m = __ballot(ok);
  __shared__ int wok[4];
  if ((d & 63) == 0) wok[d >> 6] = (m == 0xFFFFFFFFFFFFFFFFull) ? 1 : 0;
  __syncthreads();
  if (d == 0) out[(size_t)B * D + b] = (wok[0] & wok[1] & wok[2] & wok[3]) ? 1.0f : 0.0f;
}

extern "C" void kernel_launch(void* const* d_in, const int* in_sizes, int n_in,
                              void* d_out, int out_size, void* d_ws, size_t ws_size,
                              hipStream_t stream) {
  const float* xt       = (const float*)d_in[0];
  const float* live_x0  = (const float*)d_in[1];
  const float* live_ll  = (const float*)d_in[2];
  const float* x0n      = (const float*)d_in[3];
  const float* lln      = (const float*)d_in[4];
  const float* ts_p     = (const float*)d_in[5];
  const int*   boot_idx = (const int*)d_in[6];
  float* out = (float*)d_out;
  float* ws  = (float*)d_ws;

  float* hdrM              = ws + WS_HDR;
  unsigned* hdr            = (unsigned*)(ws + WS_HDR);
  float* bmax              = ws + WS_BMAX;
  float* logits            = ws + WS_LOGITS;
  float* act_e             = ws + WS_ACTE;
  int*   act_idx           = (int*)(ws + WS_ACTI);
  unsigned short* lut      = (unsigned short*)(ws + WS_LUT);
  float* boot              = ws + WS_BOOT;

  // zero header (act_cnt counters; M[b] overwritten by k_bmax anyway)
  hipMemsetAsync(hdr, 0, 160 * sizeof(unsigned), stream);

  k_logits<<<dim3(LBLK, B), 256, 0, stream>>>(xt, live_x0, live_ll, x0n, lln, ts_p, logits, bmax);
  k_bmax<<<dim3(B), 256, 0, stream>>>(bmax, hdrM);
  k_select<<<dim3(8, B), 256, 0, stream>>>(logits, hdrM, hdr, act_e, act_idx, lut);
  k_boot<<<dim3(NROW, B), 256, 0, stream>>>(live_x0, x0n, act_e, act_idx, hdr, lut, boot_idx, boot);
  k_final<<<dim3(B), 256, 0, stream>>>(boot, xt, ts_p, out);
}